// Round 8
// baseline (285.782 us; speedup 1.0000x reference)
//
#include <hip/hip_runtime.h>
#include <cstdint>

#define DEVFN static __device__ __forceinline__

typedef __bf16 bf16x8 __attribute__((ext_vector_type(8)));
typedef float f32x4 __attribute__((ext_vector_type(4)));
typedef float f32x16 __attribute__((ext_vector_type(16)));
typedef unsigned short us4 __attribute__((ext_vector_type(4)));

DEVFN unsigned short f2bf(float f) {
  unsigned u = __float_as_uint(f);
  u += 0x7fffu + ((u >> 16) & 1u);           // round-to-nearest-even
  return (unsigned short)(u >> 16);
}
DEVFN float bf2f(unsigned short h) { return __uint_as_float(((unsigned)h) << 16); }
DEVFN void async16(const void* g, void* l) {
  __builtin_amdgcn_global_load_lds((__attribute__((address_space(1))) const void*)g,
                                   (__attribute__((address_space(3))) void*)l, 16, 0, 0);
}
// gelu(tanh approx) == u * sigmoid(2z), z = 0.79788456*(u+0.044715u^3)
DEVFN float gelu_t(float u) {
  float z = 0.7978845608028654f * (u + 0.044715f * u * u * u);
  float zc = fminf(fmaxf(z, -15.f), 15.f);
  float e = __expf(2.f * zc);
  return u * __fdividef(e, e + 1.f);
}
DEVFN int xcd_swizzle(int lin, int total) {
  return (lin & 7) * (total >> 3) + (lin >> 3);
}
// 32x32x16 C/D layout: col=lane&31, row=(reg&3)+8*(reg>>2)+4*(lane>>5)
DEVFN int row32(int r, int lhalf) { return (r & 3) + 8 * (r >> 2) + 4 * lhalf; }

// ---------------- merged prep: rope + 5 transposes + LN1 --------------------
struct PrepArgs {
  float* rope;
  const float* W[5]; unsigned short* Wt[5]; float* cn[5];
  int N[5]; int off[6];
  const float* x; const float* g1s; unsigned short* h1; float* hrow1;
};
__global__ __launch_bounds__(256) void k_prep(PrepArgs a) {
  __shared__ float tile[32][33];
  __shared__ float part[8][32];
  __shared__ float red[12];
  const int bid = blockIdx.x, tid = threadIdx.x;
  if (bid < 256) {
    int g = bid * 256 + tid;
    int t = g >> 6, dd = g & 63, i = dd & 31;
    float fr = __expf(-0.2878231366242558f * (float)i);   // ln(1e4)/32
    float ang = (float)t * fr;
    a.rope[g] = (dd < 32) ? cosf(ang) : sinf(ang);
  } else if (bid < 9472) {
    int lin = bid - 256;
    int e = 0;
    while (lin >= a.off[e + 1]) ++e;
    int local = lin - a.off[e];
    const int N = a.N[e];
    int nbx = N >> 5;
    int tn = local % nbx, tk = local / nbx;
    const float* W = a.W[e];
    unsigned short* Wt = a.Wt[e];
    float* cn = a.cn[e];
    const int K = (e == 4) ? 3072 : 768;
    int tx = tid & 31, ty = tid >> 5;
    float acc = 0.f;
    #pragma unroll
    for (int j = 0; j < 4; ++j) {
      int r = ty + j * 8;
      float v = W[(long)(tk * 32 + r) * N + tn * 32 + tx];
      tile[r][tx] = v;
      acc += v * v;
    }
    part[ty][tx] = acc;
    __syncthreads();
    #pragma unroll
    for (int j = 0; j < 4; ++j) {
      int rr = ty + j * 8;
      Wt[(long)(tn * 32 + rr) * K + tk * 32 + tx] = f2bf(tile[tx][rr]);
    }
    if (ty == 0) {
      float s = part[0][tx];
      #pragma unroll
      for (int jj = 1; jj < 8; ++jj) s += part[jj][tx];
      atomicAdd(&cn[tn * 32 + tx], s);
    }
  } else {
    int row = bid - 9472;
    const float* xr = a.x + (long)row * 768;
    float v0 = xr[tid], v1 = xr[tid + 256], v2 = xr[tid + 512];
    float s = v0 + v1 + v2;
    float ss = v0 * v0 + v1 * v1 + v2 * v2;
    #pragma unroll
    for (int o = 32; o; o >>= 1) { s += __shfl_xor(s, o); ss += __shfl_xor(ss, o); }
    int wv = tid >> 6;
    if ((tid & 63) == 0) { red[wv] = s; red[wv + 4] = ss; }
    __syncthreads();
    s = red[0] + red[1] + red[2] + red[3];
    ss = red[4] + red[5] + red[6] + red[7];
    float mu = s * (1.f / 768.f);
    float var = ss * (1.f / 768.f) - mu * mu;
    float rs = rsqrtf(var + 1e-6f);
    float h0 = (v0 - mu) * rs * a.g1s[tid];
    float h1 = (v1 - mu) * rs * a.g1s[tid + 256];
    float h2 = (v2 - mu) * rs * a.g1s[tid + 512];
    unsigned short* hr = a.h1 + (long)row * 768;
    hr[tid] = f2bf(h0); hr[tid + 256] = f2bf(h1); hr[tid + 512] = f2bf(h2);
    float p = h0 * h0 + h1 * h1 + h2 * h2;
    #pragma unroll
    for (int o = 32; o; o >>= 1) p += __shfl_xor(p, o);
    if ((tid & 63) == 0) red[8 + wv] = p;
    __syncthreads();
    if (tid == 0) a.hrow1[row] = red[8] + red[9] + red[10] + red[11];
  }
}

// ---------------- layernorm (f32 in) -> bf16 h + row sum(h^2) ---------------
__global__ __launch_bounds__(256) void k_ln(const float* __restrict__ x,
    const float* __restrict__ g, unsigned short* __restrict__ h, float* __restrict__ row2) {
  int row = blockIdx.x, tid = threadIdx.x;
  const float* xr = x + (long)row * 768;
  float v0 = xr[tid], v1 = xr[tid + 256], v2 = xr[tid + 512];
  float s = v0 + v1 + v2;
  float ss = v0 * v0 + v1 * v1 + v2 * v2;
  #pragma unroll
  for (int o = 32; o; o >>= 1) { s += __shfl_xor(s, o); ss += __shfl_xor(ss, o); }
  __shared__ float red[12];
  int wv = tid >> 6;
  if ((tid & 63) == 0) { red[wv] = s; red[wv + 4] = ss; }
  __syncthreads();
  s = red[0] + red[1] + red[2] + red[3];
  ss = red[4] + red[5] + red[6] + red[7];
  float mu = s * (1.f / 768.f);
  float var = ss * (1.f / 768.f) - mu * mu;
  float rs = rsqrtf(var + 1e-6f);
  float h0 = (v0 - mu) * rs * g[tid];
  float h1 = (v1 - mu) * rs * g[tid + 256];
  float h2 = (v2 - mu) * rs * g[tid + 512];
  unsigned short* hr = h + (long)row * 768;
  hr[tid] = f2bf(h0); hr[tid + 256] = f2bf(h1); hr[tid + 512] = f2bf(h2);
  float p = h0 * h0 + h1 * h1 + h2 * h2;
  #pragma unroll
  for (int o = 32; o; o >>= 1) p += __shfl_xor(p, o);
  if ((tid & 63) == 0) red[8 + wv] = p;
  __syncthreads();
  if (tid == 0) row2[row] = red[8] + red[9] + red[10] + red[11];
}

// ---------------- yat GEMM (16x16 MFMA): 64x128 tile — QKV / AO only --------
constexpr int M_QKV = 0, M_AO = 1;

struct GemmArgs {
  const unsigned short* A; const unsigned short* Bt;
  const float* arow2; const float* wcol2; const float* bias; const float* alpha;
  int N; int ks;
  const float* rope;
  unsigned short* qo; unsigned short* ko; unsigned short* vo;
  const float* xf; float* xo;
};

template <int MODE, int NI, int NBM, int NBN>
__global__ __launch_bounds__(256, 4) void k_gemm(GemmArgs p) {
  __shared__ __align__(16) unsigned short As[3][2048];   // 64 x 32
  __shared__ __align__(16) unsigned short Bs[3][4096];   // 128 x 32
  const int tid = threadIdx.x, wave = tid >> 6, lane = tid & 63;
  const int quad = lane >> 4, l = lane & 15;
  constexpr int TOTAL = NBM * NBN;
  const int g = xcd_swizzle(blockIdx.x, TOTAL);
  const int bm = (g % NBM) * 64;
  const int bn = (g / NBM) * 128;
  const int ks = p.ks;
  const int wm = (wave & 1) * 32, wn = (wave >> 1) * 64;
  const f32x4 fzero = {0.f, 0.f, 0.f, 0.f};
  f32x4 acc[2][4];
  #pragma unroll
  for (int i = 0; i < 2; ++i)
    #pragma unroll
    for (int j = 0; j < 4; ++j) acc[i][j] = fzero;
  const int sw = (l >> 1) & 3;

  auto stage = [&](int s, int k0) {
    {
      int ci = tid;
      int r = ci >> 2;
      int c = (ci & 3) ^ ((r >> 1) & 3);
      async16(p.A + (long)(bm + r) * ks + k0 + c * 8, &As[s][ci * 8]);
    }
    #pragma unroll
    for (int it = 0; it < 2; ++it) {
      int ci = tid + it * 256;
      int r = ci >> 2;
      int c = (ci & 3) ^ ((r >> 1) & 3);
      async16(p.Bt + (long)(bn + r) * ks + k0 + c * 8, &Bs[s][ci * 8]);
    }
  };
  auto compute = [&](int s) {
    bf16x8 af[2], bfv[4];
    #pragma unroll
    for (int mi = 0; mi < 2; ++mi)
      af[mi] = *(const bf16x8*)&As[s][(wm + mi * 16 + l) * 32 + ((quad ^ sw) * 8)];
    #pragma unroll
    for (int ni = 0; ni < 4; ++ni)
      bfv[ni] = *(const bf16x8*)&Bs[s][(wn + ni * 16 + l) * 32 + ((quad ^ sw) * 8)];
    #pragma unroll
    for (int mi = 0; mi < 2; ++mi)
      #pragma unroll
      for (int ni = 0; ni < 4; ++ni)
        acc[mi][ni] = __builtin_amdgcn_mfma_f32_16x16x32_bf16(af[mi], bfv[ni], acc[mi][ni], 0, 0, 0);
  };
  auto iter = [&](int s, int i) {
    if (i + 1 >= NI) { asm volatile("s_waitcnt vmcnt(0)" ::: "memory"); }
    else             { asm volatile("s_waitcnt vmcnt(3)" ::: "memory"); }
    __builtin_amdgcn_s_barrier();
    asm volatile("" ::: "memory");
    if (i + 2 < NI) stage(s == 0 ? 2 : s - 1, (i + 2) * 32);
    compute(s);
  };

  stage(0, 0);
  stage(1, 32);
  int i = 0;
  while (i < NI) {
    iter(0, i); ++i;
    iter(1, i); ++i;
    iter(2, i); ++i;
  }

  const float al = p.alpha[0];
  const float nn = (float)p.N;
  const float ys = powf(sqrtf(nn) / log1pf(nn), al);
  #pragma unroll
  for (int ni = 0; ni < 4; ++ni) {
    const int j = bn + wn + ni * 16 + l;
    const float w2 = p.wcol2[j];
    const float bj = p.bias[j];
    int s3 = 0, hh = 0, dd = 0;
    if constexpr (MODE == M_QKV) { s3 = j / 768; int rem = j - s3 * 768; hh = rem >> 6; dd = rem & 63; }
    #pragma unroll
    for (int mi = 0; mi < 2; ++mi) {
      const int i0 = bm + wm + mi * 16 + quad * 4;
      float vv[4];
      #pragma unroll
      for (int rg = 0; rg < 4; ++rg) {
        const float y = acc[mi][ni][rg];
        const float dist = p.arow2[i0 + rg] + w2 - 2.f * y + 1e-6f;
        vv[rg] = (__fdividef(y * y, dist) + bj) * ys;
      }
      if constexpr (MODE == M_QKV) {
        int b = i0 >> 10, t0 = i0 & 1023;
        if (s3 == 2) {
          us4 pk = {f2bf(vv[0]), f2bf(vv[1]), f2bf(vv[2]), f2bf(vv[3])};
          *(us4*)&p.vo[((long)(b * 12 + hh) * 64 + dd) * 1024 + t0] = pk;    // V^T (B,H,D,T)
        } else {
          unsigned short* dst = (s3 == 0) ? p.qo : p.ko;                     // (B,H,T,D)
          #pragma unroll
          for (int rg = 0; rg < 4; ++rg) {
            float ro = p.rope[(t0 + rg) * 64 + dd];
            dst[((long)(b * 12 + hh) * 1024 + t0 + rg) * 64 + dd] = f2bf(vv[rg] * ro);
          }
        }
      } else {  // M_AO
        #pragma unroll
        for (int rg = 0; rg < 4; ++rg) {
          long idx = (long)(i0 + rg) * 768 + j;
          p.xo[idx] = p.xf[idx] + vv[rg];
        }
      }
    }
  }
}

// ======== 32x32x16 MFMA 128x128-tile kernels (wave = 64x64) =================
// LDS swizzle: row-major [row][32k], 4x16B chunks/row, chunk slot = c ^ (row&3).
// A/B frag (row r, khalf kh): lane reads slot (kh*2 + (l>>5)) ^ (r&3).

// ---------------- PROJ partial (split-K, bf16 slab out) ---------------------
struct PartArgs {
  const unsigned short* A; const unsigned short* Bt;
  unsigned short* partb;
};
__global__ __launch_bounds__(256, 3) void k_part32(PartArgs p) {
  constexpr int NI = 12, KS = 3072;
  __shared__ __align__(16) unsigned short As[3][4096];   // 128 x 32
  __shared__ __align__(16) unsigned short Bs[3][4096];
  const int tid = threadIdx.x, wave = tid >> 6, lane = tid & 63;
  const int l5 = lane >> 5, l31 = lane & 31;
  const int g = xcd_swizzle(blockIdx.x, 768);           // 16 x 6 x 8
  const int bm = (g % 16) * 128;
  const int rest = g / 16;
  const int bn = (rest % 6) * 128;
  const int z = rest / 6;
  const int kb = z * 384;
  const int wm = (wave & 1) * 64, wn = (wave >> 1) * 64;
  f32x16 acc[2][2];
  #pragma unroll
  for (int i = 0; i < 2; ++i)
    #pragma unroll
    for (int j = 0; j < 2; ++j)
      #pragma unroll
      for (int c = 0; c < 16; ++c) acc[i][j][c] = 0.f;

  auto stage = [&](int s, int k0) {
    #pragma unroll
    for (int it = 0; it < 2; ++it) {
      int ci = tid + it * 256;
      int r = ci >> 2;
      int c = (ci & 3) ^ (r & 3);
      async16(p.A + (long)(bm + r) * KS + kb + k0 + c * 8, &As[s][ci * 8]);
      async16(p.Bt + (long)(bn + r) * KS + kb + k0 + c * 8, &Bs[s][ci * 8]);
    }
  };
  auto compute = [&](int s) {
    #pragma unroll
    for (int kh = 0; kh < 2; ++kh) {
      bf16x8 a[2], b[2];
      #pragma unroll
      for (int mi = 0; mi < 2; ++mi) {
        int r = wm + mi * 32 + l31;
        a[mi] = *(const bf16x8*)&As[s][r * 32 + (((kh * 2 + l5) ^ (r & 3)) * 8)];
      }
      #pragma unroll
      for (int ni = 0; ni < 2; ++ni) {
        int r = wn + ni * 32 + l31;
        b[ni] = *(const bf16x8*)&Bs[s][r * 32 + (((kh * 2 + l5) ^ (r & 3)) * 8)];
      }
      #pragma unroll
      for (int mi = 0; mi < 2; ++mi)
        #pragma unroll
        for (int ni = 0; ni < 2; ++ni)
          acc[mi][ni] = __builtin_amdgcn_mfma_f32_32x32x16_bf16(a[mi], b[ni], acc[mi][ni], 0, 0, 0);
    }
  };
  auto iter = [&](int s, int i) {
    if (i + 1 >= NI) { asm volatile("s_waitcnt vmcnt(0)" ::: "memory"); }
    else             { asm volatile("s_waitcnt vmcnt(4)" ::: "memory"); }
    __builtin_amdgcn_s_barrier();
    asm volatile("" ::: "memory");
    if (i + 2 < NI) stage(s == 0 ? 2 : s - 1, (i + 2) * 32);
    compute(s);
  };

  stage(0, 0);
  stage(1, 32);
  int i = 0;
  while (i < NI) {
    iter(0, i); ++i;
    iter(1, i); ++i;
    iter(2, i); ++i;
  }

  unsigned short* slab = p.partb + (long)z * (2048 * 768);
  #pragma unroll
  for (int mi = 0; mi < 2; ++mi)
    #pragma unroll
    for (int ni = 0; ni < 2; ++ni) {
      const int j = bn + wn + ni * 32 + l31;
      #pragma unroll
      for (int rg = 0; rg < 16; ++rg) {
        const int ii = bm + wm + mi * 32 + row32(rg, l5);
        slab[(long)ii * 768 + j] = f2bf(acc[mi][ni][rg]);
      }
    }
}

// ---------------- merged FC+GATE (dual-B, 128x128, 32x32 MFMA) --------------
struct MlpArgs {
  const unsigned short* A; const unsigned short* Bf; const unsigned short* Bg;
  const float* arow2; const float* w2f; const float* w2g;
  const float* bf; const float* bg; const float* af_; const float* ag_;
  unsigned short* mlp; float* mrow2;
};
__global__ __launch_bounds__(256, 2) void k_mlp32(MlpArgs p) {
  constexpr int NI = 24, K = 768;
  __shared__ __align__(16) unsigned short As[3][4096];
  __shared__ __align__(16) unsigned short Bfs[3][4096];
  __shared__ __align__(16) unsigned short Bgs[3][4096];
  const int tid = threadIdx.x, wave = tid >> 6, lane = tid & 63;
  const int l5 = lane >> 5, l31 = lane & 31;
  const int g = xcd_swizzle(blockIdx.x, 384);           // 16 x 24
  const int bm = (g % 16) * 128, bn = (g / 16) * 128;
  const int wm = (wave & 1) * 64, wn = (wave >> 1) * 64;
  f32x16 accf[2][2], accg[2][2];
  #pragma unroll
  for (int i = 0; i < 2; ++i)
    #pragma unroll
    for (int j = 0; j < 2; ++j)
      #pragma unroll
      for (int c = 0; c < 16; ++c) { accf[i][j][c] = 0.f; accg[i][j][c] = 0.f; }

  auto stage = [&](int s, int k0) {
    #pragma unroll
    for (int it = 0; it < 2; ++it) {
      int ci = tid + it * 256;
      int r = ci >> 2;
      int c = (ci & 3) ^ (r & 3);
      async16(p.A  + (long)(bm + r) * K + k0 + c * 8, &As[s][ci * 8]);
      async16(p.Bf + (long)(bn + r) * K + k0 + c * 8, &Bfs[s][ci * 8]);
      async16(p.Bg + (long)(bn + r) * K + k0 + c * 8, &Bgs[s][ci * 8]);
    }
  };
  auto compute = [&](int s) {
    #pragma unroll
    for (int kh = 0; kh < 2; ++kh) {
      bf16x8 a[2], bfv[2], bgv[2];
      #pragma unroll
      for (int mi = 0; mi < 2; ++mi) {
        int r = wm + mi * 32 + l31;
        a[mi] = *(const bf16x8*)&As[s][r * 32 + (((kh * 2 + l5) ^ (r & 3)) * 8)];
      }
      #pragma unroll
      for (int ni = 0; ni < 2; ++ni) {
        int r = wn + ni * 32 + l31;
        int off = r * 32 + (((kh * 2 + l5) ^ (r & 3)) * 8);
        bfv[ni] = *(const bf16x8*)&Bfs[s][off];
        bgv[ni] = *(const bf16x8*)&Bgs[s][off];
      }
      #pragma unroll
      for (int mi = 0; mi < 2; ++mi)
        #pragma unroll
        for (int ni = 0; ni < 2; ++ni) {
          accf[mi][ni] = __builtin_amdgcn_mfma_f32_32x32x16_bf16(a[mi], bfv[ni], accf[mi][ni], 0, 0, 0);
          accg[mi][ni] = __builtin_amdgcn_mfma_f32_32x32x16_bf16(a[mi], bgv[ni], accg[mi][ni], 0, 0, 0);
        }
    }
  };
  auto iter = [&](int s, int i) {
    if (i + 1 >= NI) { asm volatile("s_waitcnt vmcnt(0)" ::: "memory"); }
    else             { asm volatile("s_waitcnt vmcnt(6)" ::: "memory"); }
    __builtin_amdgcn_s_barrier();
    asm volatile("" ::: "memory");
    if (i + 2 < NI) stage(s == 0 ? 2 : s - 1, (i + 2) * 32);
    compute(s);
  };

  stage(0, 0);
  stage(1, 32);
  int i = 0;
  while (i < NI) {
    iter(0, i); ++i;
    iter(1, i); ++i;
    iter(2, i); ++i;
  }

  const float ysf = powf(sqrtf(3072.f) / log1pf(3072.f), p.af_[0]);
  const float ysg = powf(sqrtf(3072.f) / log1pf(3072.f), p.ag_[0]);
  float w2f[2], w2g[2], bjf[2], bjg[2]; int js[2];
  #pragma unroll
  for (int ni = 0; ni < 2; ++ni) {
    int j = bn + wn + ni * 32 + l31;
    js[ni] = j; w2f[ni] = p.w2f[j]; w2g[ni] = p.w2g[j]; bjf[ni] = p.bf[j]; bjg[ni] = p.bg[j];
  }
  #pragma unroll
  for (int mi = 0; mi < 2; ++mi) {
    #pragma unroll
    for (int rg = 0; rg < 16; ++rg) {
      const int ii = bm + wm + mi * 32 + row32(rg, l5);
      const float a2 = p.arow2[ii];
      float rsum = 0.f;
      #pragma unroll
      for (int ni = 0; ni < 2; ++ni) {
        float yf = accf[mi][ni][rg];
        float gate = (__fdividef(yf * yf, a2 + w2f[ni] - 2.f * yf + 1e-6f) + bjf[ni]) * ysf;
        float yg = accg[mi][ni][rg];
        float u  = (__fdividef(yg * yg, a2 + w2g[ni] - 2.f * yg + 1e-6f) + bjg[ni]) * ysg;
        float out = gelu_t(u) * gate;
        p.mlp[(long)ii * 3072 + js[ni]] = f2bf(out);
        rsum += out * out;
      }
      #pragma unroll
      for (int o = 16; o; o >>= 1) rsum += __shfl_xor(rsum, o);
      if (l31 == 0) atomicAdd(&p.mrow2[ii], rsum);
    }
  }
}

// ---------------- PROJ reduce (8 bf16 slabs) + yat + residual ---------------
struct EpiArgs {
  const unsigned short* slab; const float* arow2; const float* wcol2;
  const float* bias; const float* alpha; const float* xo; float* outf;
};
__global__ __launch_bounds__(256) void k_proj_epi(EpiArgs p) {
  int g = blockIdx.x * 256 + threadIdx.x;   // 393216 = 2048*768/4
  int i = g / 192, jv = (g - i * 192) * 4;
  long base = (long)i * 768 + jv;
  f32x4 y = {0.f, 0.f, 0.f, 0.f};
  #pragma unroll
  for (int z = 0; z < 8; ++z) {
    us4 s4 = *(const us4*)(p.slab + (long)z * 1572864 + base);
    #pragma unroll
    for (int c = 0; c < 4; ++c) y[c] += bf2f(s4[c]);
  }
  const float a2 = p.arow2[i];
  const float ys = powf(sqrtf(768.f) / log1pf(768.f), p.alpha[0]);
  f32x4 xo4 = *(const f32x4*)(p.xo + base);
  f32x4 out;
  #pragma unroll
  for (int c = 0; c < 4; ++c) {
    float yy = y[c];
    float dist = a2 + p.wcol2[jv + c] - 2.f * yy + 1e-6f;
    out[c] = xo4[c] + (__fdividef(yy * yy, dist) + p.bias[jv + c]) * ys;
  }
  *(f32x4*)(p.outf + base) = out;
}

// ---------------- flash attention: 64-row Q tiles, causal, prefetched -------
__global__ __launch_bounds__(256) void k_attn(const unsigned short* __restrict__ qb,
    const unsigned short* __restrict__ kb, const unsigned short* __restrict__ vb,
    unsigned short* __restrict__ ob, float* __restrict__ orow2) {
  __shared__ __align__(16) unsigned short Qs[4096];
  __shared__ __align__(16) unsigned short Ks[3][4096];
  __shared__ __align__(16) unsigned short Vs[3][4096];
  __shared__ __align__(16) unsigned short Ps[4096];
  const int tid = threadIdx.x, wave = tid >> 6, lane = tid & 63;
  const int quad = lane >> 4, l = lane & 15;
  const int g = xcd_swizzle(blockIdx.x, 16 * 24);
  const int bh = g % 24, qt = 15 - (g / 24);   // heavy q-tiles first
  const int b = bh / 12, hh = bh % 12;
  const int q0 = qt * 64;
  const f32x4 fzero = {0.f, 0.f, 0.f, 0.f};

  auto stage_kv = [&](int s, int jt) {
    const unsigned short* kg = kb + ((long)bh * 1024 + jt * 64) * 64;
    const unsigned short* vg = vb + (long)bh * 64 * 1024 + jt * 64;
    #pragma unroll
    for (int it = 0; it < 2; ++it) {
      int ci = tid + it * 256;
      int r = ci >> 3;
      int c = (ci & 7) ^ (r & 7);
      async16(kg + (long)r * 64 + c * 8, &Ks[s][ci * 8]);
      async16(vg + (long)r * 1024 + c * 8, &Vs[s][ci * 8]);
    }
  };

  const unsigned short* qg = qb + ((long)bh * 1024 + q0) * 64;
  #pragma unroll
  for (int it = 0; it < 2; ++it) {
    int ci = tid + it * 256;
    int r = ci >> 3;
    int c = (ci & 7) ^ (r & 7);
    async16(qg + (long)r * 64 + c * 8, &Qs[ci * 8]);
  }
  stage_kv(0, 0);
  if (qt >= 1) {
    stage_kv(1, 1);
    asm volatile("s_waitcnt vmcnt(4)" ::: "memory");
  } else {
    asm volatile("s_waitcnt vmcnt(0)" ::: "memory");
  }
  __builtin_amdgcn_s_barrier();
  asm volatile("" ::: "memory");

  bf16x8 aq[2];
  #pragma unroll
  for (int ks = 0; ks < 2; ++ks)
    aq[ks] = *(const bf16x8*)&Qs[(wave * 16 + l) * 64 + (((ks * 4 + quad) ^ (l & 7)) * 8)];

  f32x4 O[4];
  float mi_[4], li[4];
  #pragma unroll
  for (int f = 0; f < 4; ++f) O[f] = fzero;
  #pragma unroll
  for (int r = 0; r < 4; ++r) { mi_[r] = -1e30f; li[r] = 0.f; }

  for (int jt = 0; jt <= qt; ++jt) {
    const int s = jt % 3;
    if (jt > 0) {
      if (jt + 1 <= qt) { asm volatile("s_waitcnt vmcnt(4)" ::: "memory"); }
      else              { asm volatile("s_waitcnt vmcnt(0)" ::: "memory"); }
      __builtin_amdgcn_s_barrier();
      asm volatile("" ::: "memory");
    }
    if (jt + 2 <= qt) stage_kv((jt + 2) % 3, jt + 2);

    f32x4 S[4];
    #pragma unroll
    for (int f = 0; f < 4; ++f) S[f] = fzero;
    #pragma unroll
    for (int ks = 0; ks < 2; ++ks) {
      #pragma unroll
      for (int f = 0; f < 4; ++f) {
        bf16x8 bk = *(const bf16x8*)&Ks[s][(f * 16 + l) * 64 + (((ks * 4 + quad) ^ (l & 7)) * 8)];
        S[f] = __builtin_amdgcn_mfma_f32_16x16x32_bf16(aq[ks], bk, S[f], 0, 0, 0);
      }
    }
    const bool diag = (jt == qt);
    #pragma unroll
    for (int f = 0; f < 4; ++f)
      #pragma unroll
      for (int r = 0; r < 4; ++r) {
        float v = S[f][r] * 0.125f;
        if (diag && (f * 16 + l > wave * 16 + quad * 4 + r)) v = -1e30f;
        S[f][r] = v;
      }
    #pragma unroll
    for (int r = 0; r < 4; ++r) {
      float mx = fmaxf(fmaxf(S[0][r], S[1][r]), fmaxf(S[2][r], S[3][r]));
      #pragma unroll
      for (int o = 8; o; o >>= 1) mx = fmaxf(mx, __shfl_xor(mx, o));
      float mnew = fmaxf(mi_[r], mx);
      float alr = __expf(mi_[r] - mnew);
      float sum = 0.f;
      #pragma unroll
      for (int f = 0; f < 4; ++f) {
        float e = __expf(S[f][r] - mnew);
        S[f][r] = e;
        sum += e;
      }
      #pragma unroll
      for (int o = 8; o; o >>= 1) sum += __shfl_xor(sum, o);
      li[r] = li[r] * alr + sum;
      #pragma unroll
      for (int f = 0; f < 4; ++f) O[f][r] *= alr;
      mi_[r] = mnew;
    }
    #pragma unroll
    for (int f = 0; f < 4; ++f)
      #pragma unroll
      for (int r = 0; r < 4; ++r) {
        int i = quad * 4 + r;
        int j = f * 16 + l;
        int pch = (j >> 3) ^ (i & 7);
        Ps[wave * 1024 + i * 64 + pch * 8 + (j & 7)] = f2bf(S[f][r]);
      }
    #pragma unroll
    for (int ks = 0; ks < 2; ++ks) {
      bf16x8 ap = *(const bf16x8*)&Ps[wave * 1024 + l * 64 + (((ks * 4 + quad) ^ (l & 7)) * 8)];
      #pragma unroll
      for (int f = 0; f < 4; ++f) {
        bf16x8 bv = *(const bf16x8*)&Vs[s][(f * 16 + l) * 64 + (((ks * 4 + quad) ^ (l & 7)) * 8)];
        O[f] = __builtin_amdgcn_mfma_f32_16x16x32_bf16(ap, bv, O[f], 0, 0, 0);
      }
    }
  }
  float inv[4];
  #pragma unroll
  for (int r = 0; r < 4; ++r) inv[r] = __fdividef(1.f, li[r]);
  #pragma unroll
  for (int f = 0; f < 4; ++f)
    #pragma unroll
    for (int r = 0; r < 4; ++r) {
      int t = q0 + wave * 16 + quad * 4 + r;
      int dd = f * 16 + l;
      ob[((long)(b * 1024 + t) * 12 + hh) * 64 + dd] = f2bf(O[f][r] * inv[r]);  // (B,T,H,D)
    }
  #pragma unroll
  for (int r = 0; r < 4; ++r) {
    float rsum = 0.f;
    #pragma unroll
    for (int f = 0; f < 4; ++f) { float v = O[f][r] * inv[r]; rsum += v * v; }
    #pragma unroll
    for (int o = 8; o; o >>= 1) rsum += __shfl_xor(rsum, o);
    if (l == 0) {
      int t = q0 + wave * 16 + quad * 4 + r;
      atomicAdd(&orow2[b * 1024 + t], rsum);
    }
  }
}

// ---------------- host ------------------------------------------------------
extern "C" void kernel_launch(void* const* d_in, const int* in_sizes, int n_in,
                              void* d_out, int out_size, void* d_ws, size_t ws_size,
                              hipStream_t stream) {
  (void)in_sizes; (void)n_in; (void)out_size;
  char* w = (char*)d_ws;
  size_t off = 0;
  auto alloc = [&](size_t bytes) -> void* {
    void* p = w + off;
    off = (off + bytes + 255) & ~(size_t)255;
    return p;
  };
  float* rope            = (float*)alloc(65536 * 4);
  unsigned short* wtqkv  = (unsigned short*)alloc((size_t)2304 * 768 * 2);
  unsigned short* wtao   = (unsigned short*)alloc((size_t)768 * 768 * 2);
  unsigned short* wtfc   = (unsigned short*)alloc((size_t)3072 * 768 * 2);
  unsigned short* wtgate = (unsigned short*)alloc((size_t)3072 * 768 * 2);
  unsigned short* wtproj = (unsigned short*)alloc((size_t)768 * 3072 * 2);
  float* zeroed          = (float*)alloc(14080 * 4);
  unsigned short* h1     = (unsigned short*)alloc((size_t)2048 * 768 * 2);
  float* hrow1           = (float*)alloc(2048 * 4);
  unsigned short* qbuf   = (unsigned short*)alloc((size_t)2048 * 768 * 2);
  unsigned short* kbuf   = (unsigned short*)alloc((size_t)2048 * 768 * 2);
  unsigned short* vbuf   = (unsigned short*)alloc((size_t)2048 * 768 * 2);
  unsigned short* obuf   = (unsigned short*)alloc((size_t)2048 * 768 * 2);
  float* xo              = (float*)alloc((size_t)2048 * 768 * 4);
  unsigned short* h2     = (unsigned short*)alloc((size_t)2048 * 768 * 2);
  float* hrow2           = (float*)alloc(2048 * 4);
  unsigned short* mlp    = (unsigned short*)alloc((size_t)2048 * 3072 * 2);
  unsigned short* slabs  = (unsigned short*)alloc((size_t)8 * 2048 * 768 * 2);  // 8 bf16 slabs
  if (off > ws_size) return;

  float* wcol2  = zeroed;
  float* orow2  = zeroed + 9984;
  float* mrow2  = zeroed + 9984 + 2048;
  float* c_qkv  = wcol2 + 0;
  float* c_ao   = wcol2 + 2304;
  float* c_fc   = wcol2 + 3072;
  float* c_gate = wcol2 + 6144;
  float* c_proj = wcol2 + 9216;

  const float* xin = (const float*)d_in[0];

  hipMemsetAsync(zeroed, 0, 14080 * 4, stream);

  PrepArgs pa;
  pa.rope = rope;
  pa.W[0] = (const float*)d_in[3];  pa.Wt[0] = wtqkv;  pa.cn[0] = c_qkv;  pa.N[0] = 2304;
  pa.W[1] = (const float*)d_in[6];  pa.Wt[1] = wtao;   pa.cn[1] = c_ao;   pa.N[1] = 768;
  pa.W[2] = (const float*)d_in[10]; pa.Wt[2] = wtfc;   pa.cn[2] = c_fc;   pa.N[2] = 3072;
  pa.W[3] = (const float*)d_in[13]; pa.Wt[3] = wtgate; pa.cn[3] = c_gate; pa.N[3] = 3072;
  pa.W[4] = (const float*)d_in[16]; pa.Wt[4] = wtproj; pa.cn[4] = c_proj; pa.N[4] = 768;
  pa.off[0] = 0; pa.off[1] = 1728; pa.off[2] = 2304; pa.off[3] = 4608;
  pa.off[4] = 6912; pa.off[5] = 9216;
  pa.x = xin; pa.g1s = (const float*)d_in[2]; pa.h1 = h1; pa.hrow1 = hrow1;
  k_prep<<<11520, 256, 0, stream>>>(pa);

  GemmArgs gq = {};
  gq.A = h1; gq.Bt = wtqkv; gq.arow2 = hrow1; gq.wcol2 = c_qkv;
  gq.bias = (const float*)d_in[4]; gq.alpha = (const float*)d_in[5];
  gq.N = 2304; gq.ks = 768;
  gq.rope = rope; gq.qo = qbuf; gq.ko = kbuf; gq.vo = vbuf;
  k_gemm<M_QKV, 24, 32, 18><<<576, 256, 0, stream>>>(gq);

  k_attn<<<384, 256, 0, stream>>>(qbuf, kbuf, vbuf, obuf, orow2);

  GemmArgs ga = {};
  ga.A = obuf; ga.Bt = wtao; ga.arow2 = orow2; ga.wcol2 = c_ao;
  ga.bias = (const float*)d_in[7]; ga.alpha = (const float*)d_in[8];
  ga.N = 768; ga.ks = 768;
  ga.xf = xin; ga.xo = xo;
  k_gemm<M_AO, 24, 32, 6><<<192, 256, 0, stream>>>(ga);

  k_ln<<<2048, 256, 0, stream>>>(xo, (const float*)d_in[9], h2, hrow2);

  MlpArgs gm = {};
  gm.A = h2; gm.Bf = wtfc; gm.Bg = wtgate; gm.arow2 = hrow2;
  gm.w2f = c_fc; gm.w2g = c_gate;
  gm.bf = (const float*)d_in[11]; gm.bg = (const float*)d_in[14];
  gm.af_ = (const float*)d_in[12]; gm.ag_ = (const float*)d_in[15];
  gm.mlp = mlp; gm.mrow2 = mrow2;
  k_mlp32<<<384, 256, 0, stream>>>(gm);

  PartArgs gp = {};
  gp.A = mlp; gp.Bt = wtproj; gp.partb = slabs;
  k_part32<<<768, 256, 0, stream>>>(gp);

  EpiArgs ge = {};
  ge.slab = slabs; ge.arow2 = mrow2; ge.wcol2 = c_proj;
  ge.bias = (const float*)d_in[17]; ge.alpha = (const float*)d_in[18];
  ge.xo = xo; ge.outf = (float*)d_out;
  k_proj_epi<<<1536, 256, 0, stream>>>(ge);
}